// Round 14
// baseline (2266.620 us; speedup 1.0000x reference)
//
#include <hip/hip_runtime.h>
#include <cstddef>
#include <cstdint>

#define LRELU(v) ((v) > 0.f ? (v) : 0.2f*(v))

constexpr int Bb = 8, Nn = 2048, Kk = 20, Mm = 2025, FD = 512;
constexpr int CMCH = 32;   // colmax row-chunks per batch

typedef __attribute__((ext_vector_type(8))) short short8v;   // 8 bf16 (4 VGPR)
typedef __attribute__((ext_vector_type(4))) float f32x4;

__device__ inline unsigned short f2bf(float x) {             // fp32 -> bf16 RNE
  unsigned int u = __float_as_uint(x);
  u += 0x7fff + ((u >> 16) & 1);
  return (unsigned short)(u >> 16);
}
__device__ inline float bf2f(unsigned short h) {
  return __uint_as_float(((unsigned int)h) << 16);
}

// ---------------- exact 3-way bf16 split: x == p0 + p1 + p2 (24 mantissa bits)
__global__ __launch_bounds__(256)
void split3_kernel(const float* __restrict__ x, unsigned short* __restrict__ o,
                   long long plane, int n) {
  for (int i = blockIdx.x * 256 + threadIdx.x; i < n; i += gridDim.x * 256) {
    float v = x[i];
    unsigned short h1 = f2bf(v);
    float r1 = v - bf2f(h1);            // exact (Sterbenz)
    unsigned short h2 = f2bf(r1);
    unsigned short h3 = f2bf(r1 - bf2f(h2));
    o[i] = h1;
    o[plane + i] = h2;
    o[2 * plane + i] = h3;
  }
}

// ---------------- MFMA split-bf16 GEMM: M x 512 @ 512 x 512^T --------------
// C = sum_{(i,j): i+j<=2} Ai*Bj (6 products, error < fp32 eps of product).
// 128x128 tile, 4 waves as 2x2 of 64x64, mfma_f32_16x16x32_bf16.
// Fragment maps (guide §3, m89-verified C/D): A row=l&15 k=(l>>4)*8+e;
// B col=l&15 k=(l>>4)*8+e; D col=l&15 row=(l>>4)*4+j.
// EPI: 1 lrelu(v*s+b), 2 relu(v+b)
template <int EPI>
__global__ __launch_bounds__(256, 2)
void gemm_mfma512_kernel(const unsigned short* __restrict__ A3, long long aplane,
                         const unsigned short* __restrict__ B3, long long bplane,
                         const float* __restrict__ scale, const float* __restrict__ bias,
                         float* __restrict__ out, int M) {
  constexpr int LDT = 40;                      // padded row (bf16), 80B = 16B-aligned
  __shared__ unsigned short As[3][128 * LDT];  // 30 KB
  __shared__ unsigned short Bs[3][128 * LDT];  // 30 KB
  int t = threadIdx.x;
  int w = t >> 6, l = t & 63;
  int wr = w >> 1, wc = w & 1;                 // wave -> 64x64 quadrant
  int lr = l & 15, lg = l >> 4;
  int row0 = blockIdx.x * 128, col0 = blockIdx.y * 128;

  f32x4 acc[4][4];
#pragma unroll
  for (int m = 0; m < 4; m++)
#pragma unroll
    for (int n = 0; n < 4; n++) acc[m][n] = (f32x4){0.f, 0.f, 0.f, 0.f};

  for (int kc = 0; kc < 512; kc += 32) {
    // stage 3 planes of A(128x32) and B(128x32) bf16
#pragma unroll
    for (int p = 0; p < 3; p++) {
#pragma unroll
      for (int r = 0; r < 2; r++) {
        int flat = r * 256 + t;
        int ar = flat >> 2, seg = flat & 3;
        int ka = kc + seg * 8;
        uint4 av = make_uint4(0u, 0u, 0u, 0u);
        int gr = row0 + ar;
        if (gr < M) av = *(const uint4*)&A3[(size_t)p * aplane + (size_t)gr * 512 + ka];
        *(uint4*)&As[p][ar * LDT + seg * 8] = av;
        uint4 bv = *(const uint4*)&B3[(size_t)p * bplane + (size_t)(col0 + ar) * 512 + ka];
        *(uint4*)&Bs[p][ar * LDT + seg * 8] = bv;
      }
    }
    __syncthreads();

    short8v afr[3][4];
#pragma unroll
    for (int p = 0; p < 3; p++)
#pragma unroll
      for (int m = 0; m < 4; m++)
        afr[p][m] = *(const short8v*)&As[p][(wr * 64 + m * 16 + lr) * LDT + lg * 8];
#pragma unroll
    for (int n = 0; n < 4; n++) {
      int bo = (wc * 64 + n * 16 + lr) * LDT + lg * 8;
      short8v b0 = *(const short8v*)&Bs[0][bo];
      short8v b1 = *(const short8v*)&Bs[1][bo];
      short8v b2 = *(const short8v*)&Bs[2][bo];
#pragma unroll
      for (int m = 0; m < 4; m++) {
        acc[m][n] = __builtin_amdgcn_mfma_f32_16x16x32_bf16(afr[0][m], b0, acc[m][n], 0, 0, 0);
        acc[m][n] = __builtin_amdgcn_mfma_f32_16x16x32_bf16(afr[0][m], b1, acc[m][n], 0, 0, 0);
        acc[m][n] = __builtin_amdgcn_mfma_f32_16x16x32_bf16(afr[1][m], b0, acc[m][n], 0, 0, 0);
        acc[m][n] = __builtin_amdgcn_mfma_f32_16x16x32_bf16(afr[0][m], b2, acc[m][n], 0, 0, 0);
        acc[m][n] = __builtin_amdgcn_mfma_f32_16x16x32_bf16(afr[1][m], b1, acc[m][n], 0, 0, 0);
        acc[m][n] = __builtin_amdgcn_mfma_f32_16x16x32_bf16(afr[2][m], b0, acc[m][n], 0, 0, 0);
      }
    }
    __syncthreads();
  }

  // epilogue: D col=lane&15, row=(lane>>4)*4+j
#pragma unroll
  for (int n = 0; n < 4; n++) {
    int col = col0 + wc * 64 + n * 16 + lr;
    float sv = 0.f, bvv = 0.f;
    if constexpr (EPI == 1) { sv = scale[col]; bvv = bias[col]; }
    if constexpr (EPI == 2) { bvv = bias[col]; }
#pragma unroll
    for (int m = 0; m < 4; m++) {
#pragma unroll
      for (int j = 0; j < 4; j++) {
        int gr = row0 + wr * 64 + m * 16 + lg * 4 + j;
        if (gr >= M) continue;
        float v = acc[m][n][j];
        if constexpr (EPI == 1) { v = v * sv + bvv; v = LRELU(v); }
        if constexpr (EPI == 2) { v = fmaxf(v + bvv, 0.f); }
        out[(size_t)gr * 512 + col] = v;
      }
    }
  }
}

// ---------------- row norms: one wave per row ----------------
__global__ __launch_bounds__(256)
void rownorm_kernel(const float* __restrict__ x, int ldx, int C,
                    float* __restrict__ norms, int rows) {
  int row = blockIdx.x * 4 + (threadIdx.x >> 6);
  int lane = threadIdx.x & 63;
  if (row >= rows) return;
  const float* xr = x + (size_t)row * ldx;
  float s = 0.f;
  for (int c = lane; c < C; c += 64) { float v = xr[c]; s += v * v; }
  for (int off = 32; off; off >>= 1) s += __shfl_xor(s, off);
  if (lane == 0) norms[row] = s;
}

// ---------------- pairwise neg-distance 32-tile (conv1, C=3 only) ----------
__global__ __launch_bounds__(256)
void dist_kernel(const float* __restrict__ x, int ldx, int C,
                 const float* __restrict__ norms,
                 float* __restrict__ dist,
                 long long xstride, long long dstride, int nstride) {
  int bz = blockIdx.z;
  x     += (size_t)bz * xstride;
  norms += (size_t)bz * nstride;
  dist  += (size_t)bz * dstride;

  __shared__ float As[32][36];
  __shared__ float Bs[32][36];
  int t  = threadIdx.x;
  int tx = t & 31, ty = t >> 5;
  int row0 = blockIdx.y * 32, col0 = blockIdx.x * 32;
  float acc[4] = {0.f, 0.f, 0.f, 0.f};

  for (int cc = 0; cc < C; cc += 32) {
    int gk = cc + tx;
    bool kok = gk < C;
#pragma unroll
    for (int i = 0; i < 4; i++) {
      int r = ty + 8 * i;
      As[tx][r] = kok ? x[(size_t)(row0 + r) * ldx + gk] : 0.f;
      Bs[tx][r] = kok ? x[(size_t)(col0 + r) * ldx + gk] : 0.f;
    }
    __syncthreads();
#pragma unroll
    for (int k = 0; k < 32; k++) {
      float bv = Bs[k][tx];
      float4 a = *(const float4*)&As[k][ty * 4];
      acc[0] += a.x * bv; acc[1] += a.y * bv;
      acc[2] += a.z * bv; acc[3] += a.w * bv;
    }
    __syncthreads();
  }
#pragma unroll
  for (int i = 0; i < 4; i++) {
    int n_ = row0 + ty * 4 + i;
    int m_ = col0 + tx;
    dist[(size_t)n_ * Nn + m_] = 2.f * acc[i] - norms[n_] - norms[m_];
  }
}

// ---------------- top-20 per row (jax.lax.top_k semantics) ----------------
__global__ __launch_bounds__(256)
void topk20_kernel(const float* __restrict__ dist, int* __restrict__ idx,
                   long long dstride) {
  int bz = blockIdx.z;
  dist += (size_t)bz * dstride;
  idx  += (size_t)bz * Nn * Kk;
  int row  = blockIdx.x * 4 + (threadIdx.x >> 6);
  int lane = threadIdx.x & 63;
  const float* dr = dist + (size_t)row * Nn;
  float v[32];
#pragma unroll
  for (int j = 0; j < 32; j++) v[j] = dr[lane + 64 * j];
  unsigned taken = 0u;
  for (int t = 0; t < Kk; t++) {
    float best = -3.4e38f; int bj = 40;
#pragma unroll
    for (int j = 0; j < 32; j++) {
      if (!(taken & (1u << j)) && v[j] > best) { best = v[j]; bj = j; }
    }
    int bm = lane + (bj << 6);
    for (int off = 32; off; off >>= 1) {
      float ob = __shfl_xor(best, off);
      int   om = __shfl_xor(bm, off);
      if (ob > best || (ob == best && om < bm)) { best = ob; bm = om; }
    }
    if (lane == 0) idx[row * Kk + t] = bm;
    if ((bm & 63) == lane) taken |= 1u << (bm >> 6);
  }
}

// ---------------- one-shot prep: wA/wD x4, decoder tails, grid ------------
__device__ inline void prep_w_dev(const float* __restrict__ w, float* __restrict__ wA,
                                  float* __restrict__ wD, int t, int C) {
  int o = t / C, c = t % C;
  float a = w[(size_t)o * 2 * C + c];
  float b = w[(size_t)o * 2 * C + C + c];
  wA[t] = a;
  wD[t] = b - a;
}

__global__ void prep_all_kernel(const float* __restrict__ w1, const float* __restrict__ w2,
                                const float* __restrict__ w3, const float* __restrict__ w4,
                                const float* __restrict__ f1w1, const float* __restrict__ f2w1,
                                float* wA1, float* wD1, float* wA2, float* wD2,
                                float* wA3, float* wD3, float* wA4, float* wD4,
                                float* wt1, float* wt2, float* grid) {
  int t = blockIdx.x * 256 + threadIdx.x;
  if (t < 192) {                       // conv1: 64x3
    prep_w_dev(w1, wA1, wD1, t, 3);
  } else if (t < 4288) {               // conv2: 64x64
    prep_w_dev(w2, wA2, wD2, t - 192, 64);
  } else if (t < 12480) {              // conv3: 128x64
    prep_w_dev(w3, wA3, wD3, t - 4288, 64);
  } else if (t < 45248) {              // conv4: 256x128
    prep_w_dev(w4, wA4, wD4, t - 12480, 128);
  } else if (t < 46272) {              // wt1: 2 x 512 (transposed tail of f1w1)
    int local = t - 45248;
    int c = local / FD, o = local % FD;
    wt1[c * FD + o] = f1w1[(size_t)o * (FD + 2) + FD + c];
  } else if (t < 47808) {              // wt2: 3 x 512
    int local = t - 46272;
    int c = local / FD, o = local % FD;
    wt2[c * FD + o] = f2w1[(size_t)o * (FD + 3) + FD + c];
  } else if (t < 49833) {              // grid 2025 x 2
    int m = t - 47808;
    int i = m / 45, j = m % 45;
    const double step = 0.6 / 44.0;    // linspace in double, cast once
    grid[m * 2 + 0] = (float)(-0.3 + step * i);
    grid[m * 2 + 1] = (float)(-0.3 + step * j);
  }
}

// ---------------- small tiled fp32 GEMM: 64x64 tile, 4x4 acc ---------------
// EPI: 0 none, 3 v+b
template <int EPI>
__global__ __launch_bounds__(256)
void gemm_kernel(const float* __restrict__ A, int lda,
                 const float* __restrict__ Bw, int ldb,
                 const float* __restrict__ scale, const float* __restrict__ bias,
                 float* __restrict__ out, int ldo,
                 int M, int Ncols, int K) {
  __shared__ float As[16][68];
  __shared__ float Bs[16][68];
  int t  = threadIdx.x;
  int lk = t & 15, lm = t >> 4;
  int tx = t & 15, ty = t >> 4;
  int row0 = blockIdx.x * 64, col0 = blockIdx.y * 64;
  float acc[4][4] = {{0.f}};

  for (int kc = 0; kc < K; kc += 16) {
    int gk = kc + lk;
    bool kok = gk < K;
#pragma unroll
    for (int i = 0; i < 4; i++) {
      int m  = lm + 16 * i;
      int gr = row0 + m;
      int gc = col0 + m;
      As[lk][m] = (kok && gr < M)     ? A[(size_t)gr * lda + gk]  : 0.f;
      Bs[lk][m] = (kok && gc < Ncols) ? Bw[(size_t)gc * ldb + gk] : 0.f;
    }
    __syncthreads();
#pragma unroll
    for (int k = 0; k < 16; k++) {
      float4 a = *(const float4*)&As[k][ty * 4];
      float4 b = *(const float4*)&Bs[k][tx * 4];
      acc[0][0] += a.x * b.x; acc[0][1] += a.x * b.y; acc[0][2] += a.x * b.z; acc[0][3] += a.x * b.w;
      acc[1][0] += a.y * b.x; acc[1][1] += a.y * b.y; acc[1][2] += a.y * b.z; acc[1][3] += a.y * b.w;
      acc[2][0] += a.z * b.x; acc[2][1] += a.z * b.y; acc[2][2] += a.z * b.z; acc[2][3] += a.z * b.w;
      acc[3][0] += a.w * b.x; acc[3][1] += a.w * b.y; acc[3][2] += a.w * b.z; acc[3][3] += a.w * b.w;
    }
    __syncthreads();
  }

  float bv[4] = {0.f,0.f,0.f,0.f};
#pragma unroll
  for (int j = 0; j < 4; j++) {
    int c = col0 + tx * 4 + j;
    if constexpr (EPI == 3) { bv[j] = bias[c]; }
  }
#pragma unroll
  for (int i = 0; i < 4; i++) {
    int gr = row0 + ty * 4 + i;
    if (gr >= M) continue;
    float r[4];
#pragma unroll
    for (int j = 0; j < 4; j++) {
      float v = acc[i][j];
      if constexpr (EPI == 3) { v = v + bv[j]; }
      r[j] = v;
    }
    *(float4*)&out[(size_t)gr * ldo + col0 + tx * 4] = make_float4(r[0], r[1], r[2], r[3]);
  }
}

// ---------------- big fp32 GEMM: 128x128 tile, BK=32, 8x8 acc --------------
// ROUND-5 VERBATIM (proven 80 VGPR). Used ONLY for dist (EPI=4).
// Do NOT add prefetch/swizzle: both tipped regalloc 80 -> 256 VGPR (r6, r8).
template <int EPI>
__global__ __launch_bounds__(256)
void gemm_big_kernel(const float* __restrict__ A, int lda, long long astride,
                     const float* __restrict__ Bw, int ldb, long long bstride,
                     const float* __restrict__ rn, const float* __restrict__ cn,
                     int nstride,
                     const float* __restrict__ scale, const float* __restrict__ bias,
                     float* __restrict__ out, int ldo, long long ostride,
                     int M, int K) {
  int bz = blockIdx.z;
  A   += (size_t)bz * astride;
  Bw  += (size_t)bz * bstride;
  out += (size_t)bz * ostride;
  if constexpr (EPI == 4) { rn += (size_t)bz * nstride; cn += (size_t)bz * nstride; }

  __shared__ float As[32][132];
  __shared__ float Bs[32][132];
  int t  = threadIdx.x;
  int tx = t & 15, ty = t >> 4;
  int row0 = blockIdx.x * 128, col0 = blockIdx.y * 128;

  int lr = t >> 3;
  int lk = (t & 7) * 4;

  float acc[8][8] = {{0.f}};

  for (int kc = 0; kc < K; kc += 32) {
#pragma unroll
    for (int g = 0; g < 4; g++) {
      int r  = lr + 32 * g;
      int gr = row0 + r;
      float4 av = make_float4(0.f, 0.f, 0.f, 0.f);
      if (gr < M) av = *(const float4*)&A[(size_t)gr * lda + kc + lk];
      float4 bv = *(const float4*)&Bw[(size_t)(col0 + r) * ldb + kc + lk];
      As[lk + 0][r] = av.x; As[lk + 1][r] = av.y; As[lk + 2][r] = av.z; As[lk + 3][r] = av.w;
      Bs[lk + 0][r] = bv.x; Bs[lk + 1][r] = bv.y; Bs[lk + 2][r] = bv.z; Bs[lk + 3][r] = bv.w;
    }
    __syncthreads();
#pragma unroll
    for (int k = 0; k < 32; k++) {
      float4 a0 = *(const float4*)&As[k][ty * 4];
      float4 a1 = *(const float4*)&As[k][64 + ty * 4];
      float4 b0 = *(const float4*)&Bs[k][tx * 4];
      float4 b1 = *(const float4*)&Bs[k][64 + tx * 4];
      float a[8] = {a0.x, a0.y, a0.z, a0.w, a1.x, a1.y, a1.z, a1.w};
      float b[8] = {b0.x, b0.y, b0.z, b0.w, b1.x, b1.y, b1.z, b1.w};
#pragma unroll
      for (int i = 0; i < 8; i++)
#pragma unroll
        for (int j = 0; j < 8; j++)
          acc[i][j] += a[i] * b[j];
    }
    __syncthreads();
  }

  int gcol[8];
  float cnv[8];
#pragma unroll
  for (int j = 0; j < 8; j++) {
    int c = (j < 4) ? (tx * 4 + j) : (64 + tx * 4 + (j - 4));
    gcol[j] = col0 + c;
    if constexpr (EPI == 4) { cnv[j] = cn[gcol[j]]; }
  }
#pragma unroll
  for (int i = 0; i < 8; i++) {
    int r  = (i < 4) ? (ty * 4 + i) : (64 + ty * 4 + (i - 4));
    int gr = row0 + r;
    if (gr >= M) continue;
    float rni = 0.f;
    if constexpr (EPI == 4) rni = rn[gr];
    float res[8];
#pragma unroll
    for (int j = 0; j < 8; j++) {
      float v = acc[i][j];
      if constexpr (EPI == 4) { v = 2.f * v - rni - cnv[j]; }
      res[j] = v;
    }
    *(float4*)&out[(size_t)gr * ldo + gcol[0]] = make_float4(res[0], res[1], res[2], res[3]);
    *(float4*)&out[(size_t)gr * ldo + gcol[4]] = make_float4(res[4], res[5], res[6], res[7]);
  }
}

// ---------------- med fp32 GEMM: 128x64 tile, BK=32, 8x4 acc ---------------
// Used for PQ convs (r11-benched, neutral vs big). EPI: 0 none
template <int EPI>
__global__ __launch_bounds__(256)
void gemm_med_kernel(const float* __restrict__ A, int lda,
                     const float* __restrict__ Bw, int ldb,
                     const float* __restrict__ scale, const float* __restrict__ bias,
                     float* __restrict__ out, int ldo,
                     int M, int K) {
  __shared__ float As[32][132];
  __shared__ float Bs[32][68];
  int t  = threadIdx.x;
  int tx = t & 15, ty = t >> 4;
  int row0 = blockIdx.x * 128, col0 = blockIdx.y * 64;

  int lr = t >> 3;
  int lk = (t & 7) * 4;

  float acc[8][4] = {{0.f}};

  for (int kc = 0; kc < K; kc += 32) {
#pragma unroll
    for (int g = 0; g < 4; g++) {
      int r  = lr + 32 * g;
      int gr = row0 + r;
      float4 av = make_float4(0.f, 0.f, 0.f, 0.f);
      if (gr < M) av = *(const float4*)&A[(size_t)gr * lda + kc + lk];
      As[lk + 0][r] = av.x; As[lk + 1][r] = av.y; As[lk + 2][r] = av.z; As[lk + 3][r] = av.w;
    }
#pragma unroll
    for (int g = 0; g < 2; g++) {
      int r = lr + 32 * g;
      float4 bv = *(const float4*)&Bw[(size_t)(col0 + r) * ldb + kc + lk];
      Bs[lk + 0][r] = bv.x; Bs[lk + 1][r] = bv.y; Bs[lk + 2][r] = bv.z; Bs[lk + 3][r] = bv.w;
    }
    __syncthreads();
#pragma unroll
    for (int k = 0; k < 32; k++) {
      float4 a0 = *(const float4*)&As[k][ty * 4];
      float4 a1 = *(const float4*)&As[k][64 + ty * 4];
      float4 b0 = *(const float4*)&Bs[k][tx * 4];
      float a[8] = {a0.x, a0.y, a0.z, a0.w, a1.x, a1.y, a1.z, a1.w};
      float b[4] = {b0.x, b0.y, b0.z, b0.w};
#pragma unroll
      for (int i = 0; i < 8; i++)
#pragma unroll
        for (int j = 0; j < 4; j++)
          acc[i][j] += a[i] * b[j];
    }
    __syncthreads();
  }

#pragma unroll
  for (int i = 0; i < 8; i++) {
    int r  = (i < 4) ? (ty * 4 + i) : (64 + ty * 4 + (i - 4));
    int gr = row0 + r;
    if (gr >= M) continue;
    *(float4*)&out[(size_t)gr * ldo + col0 + tx * 4] =
        make_float4(acc[i][0], acc[i][1], acc[i][2], acc[i][3]);
  }
}

// ---------------- EdgeConv combine: max_k lrelu((P[idx]+Q)*s+b) -------------
__global__ void gather_max_kernel(const float* __restrict__ PQ,
                                  const int* __restrict__ idx,
                                  const float* __restrict__ s, const float* __restrict__ bi,
                                  float* __restrict__ out, int ldo, int O) {
  int n = blockIdx.x;
  int o = threadIdx.x;
  int b = n >> 11;
  int ld2 = 2 * O;
  __shared__ int sidx[Kk];
  if (o < Kk) sidx[o] = idx[(size_t)n * Kk + o];
  __syncthreads();
  float q = PQ[(size_t)n * ld2 + O + o];
  float sc = s[o], bb = bi[o];
  float m = -3.4e38f;
#pragma unroll
  for (int k = 0; k < Kk; k++) {
    int mm = sidx[k];
    float h = (PQ[((size_t)(b * Nn + mm)) * ld2 + o] + q) * sc + bb;
    h = LRELU(h);
    m = fmaxf(m, h);
  }
  out[(size_t)n * ldo + o] = m;
}

// ---------------- column max over N per batch: two-pass --------------------
__global__ __launch_bounds__(256)
void colmax_part_kernel(const float* __restrict__ x0, float* __restrict__ part) {
  int b = blockIdx.x;
  int o = blockIdx.y * 256 + threadIdx.x;
  int ch = blockIdx.z;
  const int ROWS = Nn / CMCH;
  const float* p = x0 + ((size_t)b * Nn + (size_t)ch * ROWS) * FD + o;
  float m = -3.4e38f;
  for (int n = 0; n < ROWS; n++) m = fmaxf(m, p[(size_t)n * FD]);
  part[((size_t)b * CMCH + ch) * FD + o] = m;
}

__global__ __launch_bounds__(256)
void colmax_final_kernel(const float* __restrict__ part, float* __restrict__ feat) {
  int b = blockIdx.x;
  int o = blockIdx.y * 256 + threadIdx.x;
  const float* p = part + (size_t)b * CMCH * FD + o;
  float m = -3.4e38f;
  for (int c = 0; c < CMCH; c++) m = fmaxf(m, p[(size_t)c * FD]);
  feat[b * FD + o] = m;
}

// h1[r,o] = relu(fb[b,o] + sum_c extra[er,c]*wt[c,o])
__global__ __launch_bounds__(512)
void fold_l1_kernel(const float* __restrict__ fb, const float* __restrict__ extra,
                    int ec, int emod, const float* __restrict__ wt,
                    float* __restrict__ out) {
  int r = blockIdx.x;
  int o = threadIdx.x;
  int b = r / Mm;
  int er = emod ? (r % emod) : r;
  float v = fb[b * FD + o];
  for (int c = 0; c < ec; c++) v += extra[(size_t)er * ec + c] * wt[c * FD + o];
  out[(size_t)r * FD + o] = fmaxf(v, 0.f);
}

// out[r,0..2] = A[r,:]·W[o,:] + bias, wave per row
__global__ __launch_bounds__(256)
void gemm_o3_kernel(const float* __restrict__ A, const float* __restrict__ W,
                    const float* __restrict__ bias, float* __restrict__ out, int M) {
  int r = blockIdx.x * 4 + (threadIdx.x >> 6);
  int lane = threadIdx.x & 63;
  if (r >= M) return;
  const float* ar = A + (size_t)r * FD;
  float a0 = 0.f, a1 = 0.f, a2 = 0.f;
  for (int c = lane; c < FD; c += 64) {
    float av = ar[c];
    a0 += av * W[c];
    a1 += av * W[FD + c];
    a2 += av * W[2 * FD + c];
  }
  for (int off = 32; off; off >>= 1) {
    a0 += __shfl_xor(a0, off);
    a1 += __shfl_xor(a1, off);
    a2 += __shfl_xor(a2, off);
  }
  if (lane == 0) {
    out[r * 3 + 0] = a0 + bias[0];
    out[r * 3 + 1] = a1 + bias[1];
    out[r * 3 + 2] = a2 + bias[2];
  }
}

// ===========================================================================
extern "C" void kernel_launch(void* const* d_in, const int* in_sizes, int n_in,
                              void* d_out, int out_size, void* d_ws, size_t ws_size,
                              hipStream_t stream) {
  const float* points = (const float*)d_in[0];
  const float* w1 = (const float*)d_in[1],  *s1 = (const float*)d_in[2],  *b1 = (const float*)d_in[3];
  const float* w2 = (const float*)d_in[4],  *s2 = (const float*)d_in[5],  *b2 = (const float*)d_in[6];
  const float* w3 = (const float*)d_in[7],  *s3 = (const float*)d_in[8],  *b3 = (const float*)d_in[9];
  const float* w4 = (const float*)d_in[10], *s4 = (const float*)d_in[11], *b4 = (const float*)d_in[12];
  const float* w5 = (const float*)d_in[13], *s5 = (const float*)d_in[14], *b5 = (const float*)d_in[15];
  const float* f1w1 = (const float*)d_in[16], *f1b1 = (const float*)d_in[17];
  const float* f1w2 = (const float*)d_in[18], *f1b2 = (const float*)d_in[19];
  const float* f1w3 = (const float*)d_in[20], *f1b3 = (const float*)d_in[21];
  const float* f2w1 = (const float*)d_in[22], *f2b1 = (const float*)d_in[23];
  const float* f2w2 = (const float*)d_in[24], *f2b2 = (const float*)d_in[25];
  const float* f2w3 = (const float*)d_in[26], *f2b3 = (const float*)d_in[27];

  float* ws = (float*)d_ws;
  size_t off = 0;
  auto alloc = [&](size_t n) { float* p = ws + off; off += (n + 63) & ~(size_t)63; return p; };

  const int BN = Bb * Nn;                    // 16384
  const long long WPL = 262144;              // weight plane stride (512*512)
  const long long APL = (long long)BN * FD;  // activation plane stride
  float* p_feat = alloc(Bb * FD);
  float* p_fr1  = alloc(Bb * Mm * 3);
  float* p_norm = alloc(BN);
  int*   p_idx  = (int*)alloc((size_t)BN * Kk);
  float* p_wA1  = alloc(64 * 3);    float* p_wD1 = alloc(64 * 3);
  float* p_wA2  = alloc(64 * 64);   float* p_wD2 = alloc(64 * 64);
  float* p_wA3  = alloc(128 * 64);  float* p_wD3 = alloc(128 * 64);
  float* p_wA4  = alloc(256 * 128); float* p_wD4 = alloc(256 * 128);
  float* p_grid = alloc(Mm * 2);
  float* p_wt1  = alloc(2 * FD);
  float* p_wt2  = alloc(3 * FD);
  float* p_fb   = alloc(Bb * FD);
  float* p_part = alloc((size_t)Bb * CMCH * FD);
  unsigned short* p_w5s   = (unsigned short*)alloc(3 * WPL / 2);  // bf16 planes
  unsigned short* p_f1w2s = (unsigned short*)alloc(3 * WPL / 2);
  unsigned short* p_f2w2s = (unsigned short*)alloc(3 * WPL / 2);
  unsigned short* p_As    = (unsigned short*)alloc(3 * (size_t)APL / 2);  // 50 MB
  float* p_xc   = alloc((size_t)BN * FD);
  float* p_PQ   = alloc((size_t)BN * 512);
  float* p_H    = alloc((size_t)BN * FD);
  float* p_H2   = p_xc;

  size_t distN = (size_t)Nn * Nn;
  bool bigws = ws_size >= (off + (size_t)Bb * distN) * sizeof(float);
  float* p_dist = bigws ? (ws + off) : p_PQ;

  // ---- one-shot prep ----
  prep_all_kernel<<<195, 256, 0, stream>>>(w1, w2, w3, w4, f1w1, f2w1,
                                           p_wA1, p_wD1, p_wA2, p_wD2,
                                           p_wA3, p_wD3, p_wA4, p_wD4,
                                           p_wt1, p_wt2, p_grid);
  split3_kernel<<<512, 256, 0, stream>>>(w5,   p_w5s,   WPL, (int)WPL);
  split3_kernel<<<512, 256, 0, stream>>>(f1w2, p_f1w2s, WPL, (int)WPL);
  split3_kernel<<<512, 256, 0, stream>>>(f2w2, p_f2w2s, WPL, (int)WPL);

  auto edgeconv = [&](const float* x, int ldx, int C, int O,
                      const float* wA, const float* sc, const float* bb,
                      float* outp, int ldo) {
    rownorm_kernel<<<BN / 4, 256, 0, stream>>>(x, ldx, C, p_norm, BN);
    if (C == 3) {
      if (bigws) {
        dist_kernel<<<dim3(64, 64, Bb), 256, 0, stream>>>(
            x, ldx, C, p_norm, p_dist, (long long)Nn * ldx, (long long)distN, Nn);
        topk20_kernel<<<dim3(Nn / 4, 1, Bb), 256, 0, stream>>>(p_dist, p_idx, (long long)distN);
      } else {
        for (int b = 0; b < Bb; b++) {
          dist_kernel<<<dim3(64, 64, 1), 256, 0, stream>>>(
              x + (size_t)b * Nn * ldx, ldx, C, p_norm + b * Nn, p_dist, 0, 0, 0);
          topk20_kernel<<<dim3(Nn / 4, 1, 1), 256, 0, stream>>>(
              p_dist, p_idx + (size_t)b * Nn * Kk, 0);
        }
      }
    } else {
      if (bigws) {
        gemm_big_kernel<4><<<dim3(16, 16, Bb), 256, 0, stream>>>(
            x, ldx, (long long)Nn * ldx, x, ldx, (long long)Nn * ldx,
            p_norm, p_norm, Nn, nullptr, nullptr,
            p_dist, Nn, (long long)distN, Nn, C);
        topk20_kernel<<<dim3(Nn / 4, 1, Bb), 256, 0, stream>>>(p_dist, p_idx, (long long)distN);
      } else {
        for (int b = 0; b < Bb; b++) {
          gemm_big_kernel<4><<<dim3(16, 16, 1), 256, 0, stream>>>(
              x + (size_t)b * Nn * ldx, ldx, 0, x + (size_t)b * Nn * ldx, ldx, 0,
              p_norm + b * Nn, p_norm + b * Nn, 0, nullptr, nullptr,
              p_dist, Nn, 0, Nn, C);
          topk20_kernel<<<dim3(Nn / 4, 1, 1), 256, 0, stream>>>(
              p_dist, p_idx + (size_t)b * Nn * Kk, 0);
        }
      }
    }
    int N2 = 2 * O;
    if (C % 32 == 0) {
      gemm_med_kernel<0><<<dim3(BN / 128, N2 / 64), 256, 0, stream>>>(
          x, ldx, wA, C, nullptr, nullptr, p_PQ, N2, BN, C);
    } else {
      gemm_kernel<0><<<dim3(BN / 64, N2 / 64), 256, 0, stream>>>(
          x, ldx, wA, C, nullptr, nullptr, p_PQ, N2, BN, N2, C);
    }
    gather_max_kernel<<<BN, O, 0, stream>>>(p_PQ, p_idx, sc, bb, outp, ldo, O);
  };

  // ---- encoder ----
  edgeconv(points,     3,  3,   64,  p_wA1, s1, b1, p_xc + 0,   FD);
  edgeconv(p_xc + 0,   FD, 64,  64,  p_wA2, s2, b2, p_xc + 64,  FD);
  edgeconv(p_xc + 64,  FD, 64,  128, p_wA3, s3, b3, p_xc + 128, FD);
  edgeconv(p_xc + 128, FD, 128, 256, p_wA4, s4, b4, p_xc + 256, FD);

  // w5: split-bf16 MFMA
  split3_kernel<<<2048, 256, 0, stream>>>(p_xc, p_As, APL, BN * FD);
  gemm_mfma512_kernel<1><<<dim3(BN / 128, 4), 256, 0, stream>>>(
      p_As, APL, p_w5s, WPL, s5, b5, p_H, BN);
  colmax_part_kernel<<<dim3(Bb, FD / 256, CMCH), 256, 0, stream>>>(p_H, p_part);
  colmax_final_kernel<<<dim3(Bb, FD / 256), 256, 0, stream>>>(p_part, p_feat);

  const int MD = Bb * Mm;  // 16200
  const int GXM = (MD + 127) / 128;
  // ---- fold 1 ----
  gemm_kernel<3><<<dim3(1, FD / 64), 256, 0, stream>>>(
      p_feat, FD, f1w1, FD + 2, nullptr, f1b1, p_fb, FD, Bb, FD, FD);
  fold_l1_kernel<<<MD, FD, 0, stream>>>(p_fb, p_grid, 2, Mm, p_wt1, p_H);
  split3_kernel<<<2048, 256, 0, stream>>>(p_H, p_As, APL, MD * FD);
  gemm_mfma512_kernel<2><<<dim3(GXM, 4), 256, 0, stream>>>(
      p_As, APL, p_f1w2s, WPL, nullptr, f1b2, p_H2, MD);
  gemm_o3_kernel<<<(MD + 3) / 4, 256, 0, stream>>>(p_H2, f1w3, f1b3, p_fr1, MD);

  // ---- fold 2 ----
  gemm_kernel<3><<<dim3(1, FD / 64), 256, 0, stream>>>(
      p_feat, FD, f2w1, FD + 3, nullptr, f2b1, p_fb, FD, Bb, FD, FD);
  fold_l1_kernel<<<MD, FD, 0, stream>>>(p_fb, p_fr1, 3, 0, p_wt2, p_H);
  split3_kernel<<<2048, 256, 0, stream>>>(p_H, p_As, APL, MD * FD);
  gemm_mfma512_kernel<2><<<dim3(GXM, 4), 256, 0, stream>>>(
      p_As, APL, p_f2w2s, WPL, nullptr, f2b2, p_H2, MD);
  gemm_o3_kernel<<<(MD + 3) / 4, 256, 0, stream>>>(p_H2, f2w3, f2b3, (float*)d_out, MD);
}

// Round 15
// 1255.079 us; speedup vs baseline: 1.8060x; 1.8060x over previous
//
#include <hip/hip_runtime.h>
#include <cstddef>
#include <cstdint>

#define LRELU(v) ((v) > 0.f ? (v) : 0.2f*(v))

constexpr int Bb = 8, Nn = 2048, Kk = 20, Mm = 2025, FD = 512;
constexpr int CMCH = 32;   // colmax row-chunks per batch

typedef __attribute__((ext_vector_type(8))) short short8v;   // 8 bf16 (4 VGPR)
typedef __attribute__((ext_vector_type(4))) float f32x4;

__device__ inline unsigned short f2bf(float x) {             // fp32 -> bf16 RNE
  unsigned int u = __float_as_uint(x);
  u += 0x7fff + ((u >> 16) & 1);
  return (unsigned short)(u >> 16);
}
__device__ inline float bf2f(unsigned short h) {
  return __uint_as_float(((unsigned int)h) << 16);
}

// ---------------- exact 3-way bf16 split: x == p0 + p1 + p2 (24 mantissa bits)
__global__ __launch_bounds__(256)
void split3_kernel(const float* __restrict__ x, unsigned short* __restrict__ o,
                   long long plane, int n) {
  for (int i = blockIdx.x * 256 + threadIdx.x; i < n; i += gridDim.x * 256) {
    float v = x[i];
    unsigned short h1 = f2bf(v);
    float r1 = v - bf2f(h1);            // exact (Sterbenz)
    unsigned short h2 = f2bf(r1);
    unsigned short h3 = f2bf(r1 - bf2f(h2));
    o[i] = h1;
    o[plane + i] = h2;
    o[2 * plane + i] = h3;
  }
}

// ---------------- MFMA split-bf16 GEMM: M x 512 @ 512 x 512^T --------------
// r14-PROVEN (passed, absmax unchanged, <=82us/dispatch).
// C = sum_{(i,j): i+j<=2} Ai*Bj (6 products, error < fp32 eps of product).
// EPI: 1 lrelu(v*s+b), 2 relu(v+b)
template <int EPI>
__global__ __launch_bounds__(256, 2)
void gemm_mfma512_kernel(const unsigned short* __restrict__ A3, long long aplane,
                         const unsigned short* __restrict__ B3, long long bplane,
                         const float* __restrict__ scale, const float* __restrict__ bias,
                         float* __restrict__ out, int M) {
  constexpr int LDT = 40;                      // padded row (bf16), 80B = 16B-aligned
  __shared__ unsigned short As[3][128 * LDT];  // 30 KB
  __shared__ unsigned short Bs[3][128 * LDT];  // 30 KB
  int t = threadIdx.x;
  int w = t >> 6, l = t & 63;
  int wr = w >> 1, wc = w & 1;                 // wave -> 64x64 quadrant
  int lr = l & 15, lg = l >> 4;
  int row0 = blockIdx.x * 128, col0 = blockIdx.y * 128;

  f32x4 acc[4][4];
#pragma unroll
  for (int m = 0; m < 4; m++)
#pragma unroll
    for (int n = 0; n < 4; n++) acc[m][n] = (f32x4){0.f, 0.f, 0.f, 0.f};

  for (int kc = 0; kc < 512; kc += 32) {
#pragma unroll
    for (int p = 0; p < 3; p++) {
#pragma unroll
      for (int r = 0; r < 2; r++) {
        int flat = r * 256 + t;
        int ar = flat >> 2, seg = flat & 3;
        int ka = kc + seg * 8;
        uint4 av = make_uint4(0u, 0u, 0u, 0u);
        int gr = row0 + ar;
        if (gr < M) av = *(const uint4*)&A3[(size_t)p * aplane + (size_t)gr * 512 + ka];
        *(uint4*)&As[p][ar * LDT + seg * 8] = av;
        uint4 bv = *(const uint4*)&B3[(size_t)p * bplane + (size_t)(col0 + ar) * 512 + ka];
        *(uint4*)&Bs[p][ar * LDT + seg * 8] = bv;
      }
    }
    __syncthreads();

    short8v afr[3][4];
#pragma unroll
    for (int p = 0; p < 3; p++)
#pragma unroll
      for (int m = 0; m < 4; m++)
        afr[p][m] = *(const short8v*)&As[p][(wr * 64 + m * 16 + lr) * LDT + lg * 8];
#pragma unroll
    for (int n = 0; n < 4; n++) {
      int bo = (wc * 64 + n * 16 + lr) * LDT + lg * 8;
      short8v b0 = *(const short8v*)&Bs[0][bo];
      short8v b1 = *(const short8v*)&Bs[1][bo];
      short8v b2 = *(const short8v*)&Bs[2][bo];
#pragma unroll
      for (int m = 0; m < 4; m++) {
        acc[m][n] = __builtin_amdgcn_mfma_f32_16x16x32_bf16(afr[0][m], b0, acc[m][n], 0, 0, 0);
        acc[m][n] = __builtin_amdgcn_mfma_f32_16x16x32_bf16(afr[0][m], b1, acc[m][n], 0, 0, 0);
        acc[m][n] = __builtin_amdgcn_mfma_f32_16x16x32_bf16(afr[1][m], b0, acc[m][n], 0, 0, 0);
        acc[m][n] = __builtin_amdgcn_mfma_f32_16x16x32_bf16(afr[0][m], b2, acc[m][n], 0, 0, 0);
        acc[m][n] = __builtin_amdgcn_mfma_f32_16x16x32_bf16(afr[1][m], b1, acc[m][n], 0, 0, 0);
        acc[m][n] = __builtin_amdgcn_mfma_f32_16x16x32_bf16(afr[2][m], b0, acc[m][n], 0, 0, 0);
      }
    }
    __syncthreads();
  }

  // epilogue: D col=lane&15, row=(lane>>4)*4+j
#pragma unroll
  for (int n = 0; n < 4; n++) {
    int col = col0 + wc * 64 + n * 16 + lr;
    float sv = 0.f, bvv = 0.f;
    if constexpr (EPI == 1) { sv = scale[col]; bvv = bias[col]; }
    if constexpr (EPI == 2) { bvv = bias[col]; }
#pragma unroll
    for (int m = 0; m < 4; m++) {
#pragma unroll
      for (int j = 0; j < 4; j++) {
        int gr = row0 + wr * 64 + m * 16 + lg * 4 + j;
        if (gr >= M) continue;
        float v = acc[m][n][j];
        if constexpr (EPI == 1) { v = v * sv + bvv; v = LRELU(v); }
        if constexpr (EPI == 2) { v = fmaxf(v + bvv, 0.f); }
        out[(size_t)gr * 512 + col] = v;
      }
    }
  }
}

// ---------------- fb: out[r,o] = feat[r,:512]·W[o,:512] + bias[o] ----------
// One wave per output element (4096 waves, 1024 blocks). Replaces the 8-block
// gemm_kernel<3> launches (r14 profile: 82us @ 0.33% occupancy each).
__global__ __launch_bounds__(256)
void fb_kernel(const float* __restrict__ feat, const float* __restrict__ W, int ldw,
               const float* __restrict__ bias, float* __restrict__ out) {
  int e = blockIdx.x * 4 + (threadIdx.x >> 6);   // 0..4095
  int lane = threadIdx.x & 63;
  int r = e >> 9, o = e & 511;
  const float* fr = feat + r * FD;
  const float* wr = W + (size_t)o * ldw;
  float s = 0.f;
#pragma unroll
  for (int i = 0; i < 8; i++) {
    int c = lane + 64 * i;
    s += fr[c] * wr[c];
  }
  for (int off = 32; off; off >>= 1) s += __shfl_xor(s, off);
  if (lane == 0) out[r * FD + o] = s + bias[o];
}

// ---------------- row norms: one wave per row ----------------
__global__ __launch_bounds__(256)
void rownorm_kernel(const float* __restrict__ x, int ldx, int C,
                    float* __restrict__ norms, int rows) {
  int row = blockIdx.x * 4 + (threadIdx.x >> 6);
  int lane = threadIdx.x & 63;
  if (row >= rows) return;
  const float* xr = x + (size_t)row * ldx;
  float s = 0.f;
  for (int c = lane; c < C; c += 64) { float v = xr[c]; s += v * v; }
  for (int off = 32; off; off >>= 1) s += __shfl_xor(s, off);
  if (lane == 0) norms[row] = s;
}

// ---------------- pairwise neg-distance 32-tile (conv1, C=3 only) ----------
__global__ __launch_bounds__(256)
void dist_kernel(const float* __restrict__ x, int ldx, int C,
                 const float* __restrict__ norms,
                 float* __restrict__ dist,
                 long long xstride, long long dstride, int nstride) {
  int bz = blockIdx.z;
  x     += (size_t)bz * xstride;
  norms += (size_t)bz * nstride;
  dist  += (size_t)bz * dstride;

  __shared__ float As[32][36];
  __shared__ float Bs[32][36];
  int t  = threadIdx.x;
  int tx = t & 31, ty = t >> 5;
  int row0 = blockIdx.y * 32, col0 = blockIdx.x * 32;
  float acc[4] = {0.f, 0.f, 0.f, 0.f};

  for (int cc = 0; cc < C; cc += 32) {
    int gk = cc + tx;
    bool kok = gk < C;
#pragma unroll
    for (int i = 0; i < 4; i++) {
      int r = ty + 8 * i;
      As[tx][r] = kok ? x[(size_t)(row0 + r) * ldx + gk] : 0.f;
      Bs[tx][r] = kok ? x[(size_t)(col0 + r) * ldx + gk] : 0.f;
    }
    __syncthreads();
#pragma unroll
    for (int k = 0; k < 32; k++) {
      float bv = Bs[k][tx];
      float4 a = *(const float4*)&As[k][ty * 4];
      acc[0] += a.x * bv; acc[1] += a.y * bv;
      acc[2] += a.z * bv; acc[3] += a.w * bv;
    }
    __syncthreads();
  }
#pragma unroll
  for (int i = 0; i < 4; i++) {
    int n_ = row0 + ty * 4 + i;
    int m_ = col0 + tx;
    dist[(size_t)n_ * Nn + m_] = 2.f * acc[i] - norms[n_] - norms[m_];
  }
}

// ---------------- top-20 per row (jax.lax.top_k semantics) ----------------
__global__ __launch_bounds__(256)
void topk20_kernel(const float* __restrict__ dist, int* __restrict__ idx,
                   long long dstride) {
  int bz = blockIdx.z;
  dist += (size_t)bz * dstride;
  idx  += (size_t)bz * Nn * Kk;
  int row  = blockIdx.x * 4 + (threadIdx.x >> 6);
  int lane = threadIdx.x & 63;
  const float* dr = dist + (size_t)row * Nn;
  float v[32];
#pragma unroll
  for (int j = 0; j < 32; j++) v[j] = dr[lane + 64 * j];
  unsigned taken = 0u;
  for (int t = 0; t < Kk; t++) {
    float best = -3.4e38f; int bj = 40;
#pragma unroll
    for (int j = 0; j < 32; j++) {
      if (!(taken & (1u << j)) && v[j] > best) { best = v[j]; bj = j; }
    }
    int bm = lane + (bj << 6);
    for (int off = 32; off; off >>= 1) {
      float ob = __shfl_xor(best, off);
      int   om = __shfl_xor(bm, off);
      if (ob > best || (ob == best && om < bm)) { best = ob; bm = om; }
    }
    if (lane == 0) idx[row * Kk + t] = bm;
    if ((bm & 63) == lane) taken |= 1u << (bm >> 6);
  }
}

// ---------------- one-shot prep: wA/wD x4, decoder tails, grid ------------
__device__ inline void prep_w_dev(const float* __restrict__ w, float* __restrict__ wA,
                                  float* __restrict__ wD, int t, int C) {
  int o = t / C, c = t % C;
  float a = w[(size_t)o * 2 * C + c];
  float b = w[(size_t)o * 2 * C + C + c];
  wA[t] = a;
  wD[t] = b - a;
}

__global__ void prep_all_kernel(const float* __restrict__ w1, const float* __restrict__ w2,
                                const float* __restrict__ w3, const float* __restrict__ w4,
                                const float* __restrict__ f1w1, const float* __restrict__ f2w1,
                                float* wA1, float* wD1, float* wA2, float* wD2,
                                float* wA3, float* wD3, float* wA4, float* wD4,
                                float* wt1, float* wt2, float* grid) {
  int t = blockIdx.x * 256 + threadIdx.x;
  if (t < 192) {                       // conv1: 64x3
    prep_w_dev(w1, wA1, wD1, t, 3);
  } else if (t < 4288) {               // conv2: 64x64
    prep_w_dev(w2, wA2, wD2, t - 192, 64);
  } else if (t < 12480) {              // conv3: 128x64
    prep_w_dev(w3, wA3, wD3, t - 4288, 64);
  } else if (t < 45248) {              // conv4: 256x128
    prep_w_dev(w4, wA4, wD4, t - 12480, 128);
  } else if (t < 46272) {              // wt1: 2 x 512 (transposed tail of f1w1)
    int local = t - 45248;
    int c = local / FD, o = local % FD;
    wt1[c * FD + o] = f1w1[(size_t)o * (FD + 2) + FD + c];
  } else if (t < 47808) {              // wt2: 3 x 512
    int local = t - 46272;
    int c = local / FD, o = local % FD;
    wt2[c * FD + o] = f2w1[(size_t)o * (FD + 3) + FD + c];
  } else if (t < 49833) {              // grid 2025 x 2
    int m = t - 47808;
    int i = m / 45, j = m % 45;
    const double step = 0.6 / 44.0;    // linspace in double, cast once
    grid[m * 2 + 0] = (float)(-0.3 + step * i);
    grid[m * 2 + 1] = (float)(-0.3 + step * j);
  }
}

// ---------------- small tiled fp32 GEMM: 64x64 tile, 4x4 acc ---------------
// EPI: 0 none
template <int EPI>
__global__ __launch_bounds__(256)
void gemm_kernel(const float* __restrict__ A, int lda,
                 const float* __restrict__ Bw, int ldb,
                 const float* __restrict__ scale, const float* __restrict__ bias,
                 float* __restrict__ out, int ldo,
                 int M, int Ncols, int K) {
  __shared__ float As[16][68];
  __shared__ float Bs[16][68];
  int t  = threadIdx.x;
  int lk = t & 15, lm = t >> 4;
  int tx = t & 15, ty = t >> 4;
  int row0 = blockIdx.x * 64, col0 = blockIdx.y * 64;
  float acc[4][4] = {{0.f}};

  for (int kc = 0; kc < K; kc += 16) {
    int gk = kc + lk;
    bool kok = gk < K;
#pragma unroll
    for (int i = 0; i < 4; i++) {
      int m  = lm + 16 * i;
      int gr = row0 + m;
      int gc = col0 + m;
      As[lk][m] = (kok && gr < M)     ? A[(size_t)gr * lda + gk]  : 0.f;
      Bs[lk][m] = (kok && gc < Ncols) ? Bw[(size_t)gc * ldb + gk] : 0.f;
    }
    __syncthreads();
#pragma unroll
    for (int k = 0; k < 16; k++) {
      float4 a = *(const float4*)&As[k][ty * 4];
      float4 b = *(const float4*)&Bs[k][tx * 4];
      acc[0][0] += a.x * b.x; acc[0][1] += a.x * b.y; acc[0][2] += a.x * b.z; acc[0][3] += a.x * b.w;
      acc[1][0] += a.y * b.x; acc[1][1] += a.y * b.y; acc[1][2] += a.y * b.z; acc[1][3] += a.y * b.w;
      acc[2][0] += a.z * b.x; acc[2][1] += a.z * b.y; acc[2][2] += a.z * b.z; acc[2][3] += a.z * b.w;
      acc[3][0] += a.w * b.x; acc[3][1] += a.w * b.y; acc[3][2] += a.w * b.z; acc[3][3] += a.w * b.w;
    }
    __syncthreads();
  }

#pragma unroll
  for (int i = 0; i < 4; i++) {
    int gr = row0 + ty * 4 + i;
    if (gr >= M) continue;
    *(float4*)&out[(size_t)gr * ldo + col0 + tx * 4] =
        make_float4(acc[i][0], acc[i][1], acc[i][2], acc[i][3]);
  }
}

// ---------------- big fp32 GEMM: 128x128 tile, BK=32, 8x8 acc --------------
// ROUND-5 VERBATIM (proven 80 VGPR). Used ONLY for dist (EPI=4).
// Do NOT add prefetch/swizzle: both tipped regalloc 80 -> 256 VGPR (r6, r8).
template <int EPI>
__global__ __launch_bounds__(256)
void gemm_big_kernel(const float* __restrict__ A, int lda, long long astride,
                     const float* __restrict__ Bw, int ldb, long long bstride,
                     const float* __restrict__ rn, const float* __restrict__ cn,
                     int nstride,
                     const float* __restrict__ scale, const float* __restrict__ bias,
                     float* __restrict__ out, int ldo, long long ostride,
                     int M, int K) {
  int bz = blockIdx.z;
  A   += (size_t)bz * astride;
  Bw  += (size_t)bz * bstride;
  out += (size_t)bz * ostride;
  if constexpr (EPI == 4) { rn += (size_t)bz * nstride; cn += (size_t)bz * nstride; }

  __shared__ float As[32][132];
  __shared__ float Bs[32][132];
  int t  = threadIdx.x;
  int tx = t & 15, ty = t >> 4;
  int row0 = blockIdx.x * 128, col0 = blockIdx.y * 128;

  int lr = t >> 3;
  int lk = (t & 7) * 4;

  float acc[8][8] = {{0.f}};

  for (int kc = 0; kc < K; kc += 32) {
#pragma unroll
    for (int g = 0; g < 4; g++) {
      int r  = lr + 32 * g;
      int gr = row0 + r;
      float4 av = make_float4(0.f, 0.f, 0.f, 0.f);
      if (gr < M) av = *(const float4*)&A[(size_t)gr * lda + kc + lk];
      float4 bv = *(const float4*)&Bw[(size_t)(col0 + r) * ldb + kc + lk];
      As[lk + 0][r] = av.x; As[lk + 1][r] = av.y; As[lk + 2][r] = av.z; As[lk + 3][r] = av.w;
      Bs[lk + 0][r] = bv.x; Bs[lk + 1][r] = bv.y; Bs[lk + 2][r] = bv.z; Bs[lk + 3][r] = bv.w;
    }
    __syncthreads();
#pragma unroll
    for (int k = 0; k < 32; k++) {
      float4 a0 = *(const float4*)&As[k][ty * 4];
      float4 a1 = *(const float4*)&As[k][64 + ty * 4];
      float4 b0 = *(const float4*)&Bs[k][tx * 4];
      float4 b1 = *(const float4*)&Bs[k][64 + tx * 4];
      float a[8] = {a0.x, a0.y, a0.z, a0.w, a1.x, a1.y, a1.z, a1.w};
      float b[8] = {b0.x, b0.y, b0.z, b0.w, b1.x, b1.y, b1.z, b1.w};
#pragma unroll
      for (int i = 0; i < 8; i++)
#pragma unroll
        for (int j = 0; j < 8; j++)
          acc[i][j] += a[i] * b[j];
    }
    __syncthreads();
  }

  int gcol[8];
  float cnv[8];
#pragma unroll
  for (int j = 0; j < 8; j++) {
    int c = (j < 4) ? (tx * 4 + j) : (64 + tx * 4 + (j - 4));
    gcol[j] = col0 + c;
    if constexpr (EPI == 4) { cnv[j] = cn[gcol[j]]; }
  }
#pragma unroll
  for (int i = 0; i < 8; i++) {
    int r  = (i < 4) ? (ty * 4 + i) : (64 + ty * 4 + (i - 4));
    int gr = row0 + r;
    if (gr >= M) continue;
    float rni = 0.f;
    if constexpr (EPI == 4) rni = rn[gr];
    float res[8];
#pragma unroll
    for (int j = 0; j < 8; j++) {
      float v = acc[i][j];
      if constexpr (EPI == 4) { v = 2.f * v - rni - cnv[j]; }
      res[j] = v;
    }
    *(float4*)&out[(size_t)gr * ldo + gcol[0]] = make_float4(res[0], res[1], res[2], res[3]);
    *(float4*)&out[(size_t)gr * ldo + gcol[4]] = make_float4(res[4], res[5], res[6], res[7]);
  }
}

// ---------------- med fp32 GEMM: 128x64 tile, BK=32, 8x4 acc ---------------
// Used for PQ convs. EPI: 0 none
template <int EPI>
__global__ __launch_bounds__(256)
void gemm_med_kernel(const float* __restrict__ A, int lda,
                     const float* __restrict__ Bw, int ldb,
                     const float* __restrict__ scale, const float* __restrict__ bias,
                     float* __restrict__ out, int ldo,
                     int M, int K) {
  __shared__ float As[32][132];
  __shared__ float Bs[32][68];
  int t  = threadIdx.x;
  int tx = t & 15, ty = t >> 4;
  int row0 = blockIdx.x * 128, col0 = blockIdx.y * 64;

  int lr = t >> 3;
  int lk = (t & 7) * 4;

  float acc[8][4] = {{0.f}};

  for (int kc = 0; kc < K; kc += 32) {
#pragma unroll
    for (int g = 0; g < 4; g++) {
      int r  = lr + 32 * g;
      int gr = row0 + r;
      float4 av = make_float4(0.f, 0.f, 0.f, 0.f);
      if (gr < M) av = *(const float4*)&A[(size_t)gr * lda + kc + lk];
      As[lk + 0][r] = av.x; As[lk + 1][r] = av.y; As[lk + 2][r] = av.z; As[lk + 3][r] = av.w;
    }
#pragma unroll
    for (int g = 0; g < 2; g++) {
      int r = lr + 32 * g;
      float4 bv = *(const float4*)&Bw[(size_t)(col0 + r) * ldb + kc + lk];
      Bs[lk + 0][r] = bv.x; Bs[lk + 1][r] = bv.y; Bs[lk + 2][r] = bv.z; Bs[lk + 3][r] = bv.w;
    }
    __syncthreads();
#pragma unroll
    for (int k = 0; k < 32; k++) {
      float4 a0 = *(const float4*)&As[k][ty * 4];
      float4 a1 = *(const float4*)&As[k][64 + ty * 4];
      float4 b0 = *(const float4*)&Bs[k][tx * 4];
      float a[8] = {a0.x, a0.y, a0.z, a0.w, a1.x, a1.y, a1.z, a1.w};
      float b[4] = {b0.x, b0.y, b0.z, b0.w};
#pragma unroll
      for (int i = 0; i < 8; i++)
#pragma unroll
        for (int j = 0; j < 4; j++)
          acc[i][j] += a[i] * b[j];
    }
    __syncthreads();
  }

#pragma unroll
  for (int i = 0; i < 8; i++) {
    int r  = (i < 4) ? (ty * 4 + i) : (64 + ty * 4 + (i - 4));
    int gr = row0 + r;
    if (gr >= M) continue;
    *(float4*)&out[(size_t)gr * ldo + col0 + tx * 4] =
        make_float4(acc[i][0], acc[i][1], acc[i][2], acc[i][3]);
  }
}

// ---------------- EdgeConv combine: max_k lrelu((P[idx]+Q)*s+b) -------------
__global__ void gather_max_kernel(const float* __restrict__ PQ,
                                  const int* __restrict__ idx,
                                  const float* __restrict__ s, const float* __restrict__ bi,
                                  float* __restrict__ out, int ldo, int O) {
  int n = blockIdx.x;
  int o = threadIdx.x;
  int b = n >> 11;
  int ld2 = 2 * O;
  __shared__ int sidx[Kk];
  if (o < Kk) sidx[o] = idx[(size_t)n * Kk + o];
  __syncthreads();
  float q = PQ[(size_t)n * ld2 + O + o];
  float sc = s[o], bb = bi[o];
  float m = -3.4e38f;
#pragma unroll
  for (int k = 0; k < Kk; k++) {
    int mm = sidx[k];
    float h = (PQ[((size_t)(b * Nn + mm)) * ld2 + o] + q) * sc + bb;
    h = LRELU(h);
    m = fmaxf(m, h);
  }
  out[(size_t)n * ldo + o] = m;
}

// ---------------- column max over N per batch: two-pass --------------------
__global__ __launch_bounds__(256)
void colmax_part_kernel(const float* __restrict__ x0, float* __restrict__ part) {
  int b = blockIdx.x;
  int o = blockIdx.y * 256 + threadIdx.x;
  int ch = blockIdx.z;
  const int ROWS = Nn / CMCH;
  const float* p = x0 + ((size_t)b * Nn + (size_t)ch * ROWS) * FD + o;
  float m = -3.4e38f;
  for (int n = 0; n < ROWS; n++) m = fmaxf(m, p[(size_t)n * FD]);
  part[((size_t)b * CMCH + ch) * FD + o] = m;
}

__global__ __launch_bounds__(256)
void colmax_final_kernel(const float* __restrict__ part, float* __restrict__ feat) {
  int b = blockIdx.x;
  int o = blockIdx.y * 256 + threadIdx.x;
  const float* p = part + (size_t)b * CMCH * FD + o;
  float m = -3.4e38f;
  for (int c = 0; c < CMCH; c++) m = fmaxf(m, p[(size_t)c * FD]);
  feat[b * FD + o] = m;
}

// h1[r,o] = relu(fb[b,o] + sum_c extra[er,c]*wt[c,o])
__global__ __launch_bounds__(512)
void fold_l1_kernel(const float* __restrict__ fb, const float* __restrict__ extra,
                    int ec, int emod, const float* __restrict__ wt,
                    float* __restrict__ out) {
  int r = blockIdx.x;
  int o = threadIdx.x;
  int b = r / Mm;
  int er = emod ? (r % emod) : r;
  float v = fb[b * FD + o];
  for (int c = 0; c < ec; c++) v += extra[(size_t)er * ec + c] * wt[c * FD + o];
  out[(size_t)r * FD + o] = fmaxf(v, 0.f);
}

// out[r,0..2] = A[r,:]·W[o,:] + bias, wave per row
__global__ __launch_bounds__(256)
void gemm_o3_kernel(const float* __restrict__ A, const float* __restrict__ W,
                    const float* __restrict__ bias, float* __restrict__ out, int M) {
  int r = blockIdx.x * 4 + (threadIdx.x >> 6);
  int lane = threadIdx.x & 63;
  if (r >= M) return;
  const float* ar = A + (size_t)r * FD;
  float a0 = 0.f, a1 = 0.f, a2 = 0.f;
  for (int c = lane; c < FD; c += 64) {
    float av = ar[c];
    a0 += av * W[c];
    a1 += av * W[FD + c];
    a2 += av * W[2 * FD + c];
  }
  for (int off = 32; off; off >>= 1) {
    a0 += __shfl_xor(a0, off);
    a1 += __shfl_xor(a1, off);
    a2 += __shfl_xor(a2, off);
  }
  if (lane == 0) {
    out[r * 3 + 0] = a0 + bias[0];
    out[r * 3 + 1] = a1 + bias[1];
    out[r * 3 + 2] = a2 + bias[2];
  }
}

// ===========================================================================
extern "C" void kernel_launch(void* const* d_in, const int* in_sizes, int n_in,
                              void* d_out, int out_size, void* d_ws, size_t ws_size,
                              hipStream_t stream) {
  const float* points = (const float*)d_in[0];
  const float* w1 = (const float*)d_in[1],  *s1 = (const float*)d_in[2],  *b1 = (const float*)d_in[3];
  const float* w2 = (const float*)d_in[4],  *s2 = (const float*)d_in[5],  *b2 = (const float*)d_in[6];
  const float* w3 = (const float*)d_in[7],  *s3 = (const float*)d_in[8],  *b3 = (const float*)d_in[9];
  const float* w4 = (const float*)d_in[10], *s4 = (const float*)d_in[11], *b4 = (const float*)d_in[12];
  const float* w5 = (const float*)d_in[13], *s5 = (const float*)d_in[14], *b5 = (const float*)d_in[15];
  const float* f1w1 = (const float*)d_in[16], *f1b1 = (const float*)d_in[17];
  const float* f1w2 = (const float*)d_in[18], *f1b2 = (const float*)d_in[19];
  const float* f1w3 = (const float*)d_in[20], *f1b3 = (const float*)d_in[21];
  const float* f2w1 = (const float*)d_in[22], *f2b1 = (const float*)d_in[23];
  const float* f2w2 = (const float*)d_in[24], *f2b2 = (const float*)d_in[25];
  const float* f2w3 = (const float*)d_in[26], *f2b3 = (const float*)d_in[27];

  float* ws = (float*)d_ws;
  size_t off = 0;
  auto alloc = [&](size_t n) { float* p = ws + off; off += (n + 63) & ~(size_t)63; return p; };

  const int BN = Bb * Nn;                    // 16384
  const long long WPL = 262144;              // weight plane stride (512*512)
  const long long APL = (long long)BN * FD;  // activation plane stride (8.4M)
  float* p_feat = alloc(Bb * FD);
  float* p_fr1  = alloc(Bb * Mm * 3);
  float* p_norm = alloc(BN);
  int*   p_idx  = (int*)alloc((size_t)BN * Kk);
  float* p_wA1  = alloc(64 * 3);    float* p_wD1 = alloc(64 * 3);
  float* p_wA2  = alloc(64 * 64);   float* p_wD2 = alloc(64 * 64);
  float* p_wA3  = alloc(128 * 64);  float* p_wD3 = alloc(128 * 64);
  float* p_wA4  = alloc(256 * 128); float* p_wD4 = alloc(256 * 128);
  float* p_grid = alloc(Mm * 2);
  float* p_wt1  = alloc(2 * FD);
  float* p_wt2  = alloc(3 * FD);
  float* p_fb   = alloc(Bb * FD);
  float* p_part = alloc((size_t)Bb * CMCH * FD);
  unsigned short* p_w5s   = (unsigned short*)alloc(3 * WPL / 2);  // bf16 planes
  unsigned short* p_f1w2s = (unsigned short*)alloc(3 * WPL / 2);
  unsigned short* p_f2w2s = (unsigned short*)alloc(3 * WPL / 2);
  float* p_xc   = alloc((size_t)BN * FD);
  // PQ (conv phase) and H (w5/decoder phase) have disjoint lifetimes -> alias.
  float* p_PQ   = alloc((size_t)BN * 512);
  float* p_H    = p_PQ;
  float* p_H2   = p_xc;

  // Big transient region: dist (conv phase) UNION As bf16 planes (w5/decoder).
  // r14 LESSON: the +50MB of separate bf16 buffers flipped bigws -> per-batch
  // kNN fallback (+727us). Aliasing keeps the requirement at ~208 MB.
  size_t distN  = (size_t)Nn * Nn;                       // 4.19M floats/batch
  size_t asN    = (3 * (size_t)APL + 1) / 2;             // 12.6M floats
  bool bigws = ws_size >= (off + (size_t)Bb * distN) * sizeof(float);
  float* p_big  = alloc(bigws ? (size_t)Bb * distN : asN);
  float* p_dist = p_big;
  unsigned short* p_As = (unsigned short*)p_big;

  // ---- one-shot prep ----
  prep_all_kernel<<<195, 256, 0, stream>>>(w1, w2, w3, w4, f1w1, f2w1,
                                           p_wA1, p_wD1, p_wA2, p_wD2,
                                           p_wA3, p_wD3, p_wA4, p_wD4,
                                           p_wt1, p_wt2, p_grid);
  split3_kernel<<<512, 256, 0, stream>>>(w5,   p_w5s,   WPL, (int)WPL);
  split3_kernel<<<512, 256, 0, stream>>>(f1w2, p_f1w2s, WPL, (int)WPL);
  split3_kernel<<<512, 256, 0, stream>>>(f2w2, p_f2w2s, WPL, (int)WPL);

  auto edgeconv = [&](const float* x, int ldx, int C, int O,
                      const float* wA, const float* sc, const float* bb,
                      float* outp, int ldo) {
    rownorm_kernel<<<BN / 4, 256, 0, stream>>>(x, ldx, C, p_norm, BN);
    if (C == 3) {
      if (bigws) {
        dist_kernel<<<dim3(64, 64, Bb), 256, 0, stream>>>(
            x, ldx, C, p_norm, p_dist, (long long)Nn * ldx, (long long)distN, Nn);
        topk20_kernel<<<dim3(Nn / 4, 1, Bb), 256, 0, stream>>>(p_dist, p_idx, (long long)distN);
      } else {
        for (int b = 0; b < Bb; b++) {
          dist_kernel<<<dim3(64, 64, 1), 256, 0, stream>>>(
              x + (size_t)b * Nn * ldx, ldx, C, p_norm + b * Nn, p_dist, 0, 0, 0);
          topk20_kernel<<<dim3(Nn / 4, 1, 1), 256, 0, stream>>>(
              p_dist, p_idx + (size_t)b * Nn * Kk, 0);
        }
      }
    } else {
      if (bigws) {
        gemm_big_kernel<4><<<dim3(16, 16, Bb), 256, 0, stream>>>(
            x, ldx, (long long)Nn * ldx, x, ldx, (long long)Nn * ldx,
            p_norm, p_norm, Nn, nullptr, nullptr,
            p_dist, Nn, (long long)distN, Nn, C);
        topk20_kernel<<<dim3(Nn / 4, 1, Bb), 256, 0, stream>>>(p_dist, p_idx, (long long)distN);
      } else {
        for (int b = 0; b < Bb; b++) {
          gemm_big_kernel<4><<<dim3(16, 16, 1), 256, 0, stream>>>(
              x + (size_t)b * Nn * ldx, ldx, 0, x + (size_t)b * Nn * ldx, ldx, 0,
              p_norm + b * Nn, p_norm + b * Nn, 0, nullptr, nullptr,
              p_dist, Nn, 0, Nn, C);
          topk20_kernel<<<dim3(Nn / 4, 1, 1), 256, 0, stream>>>(
              p_dist, p_idx + (size_t)b * Nn * Kk, 0);
        }
      }
    }
    int N2 = 2 * O;
    if (C % 32 == 0) {
      gemm_med_kernel<0><<<dim3(BN / 128, N2 / 64), 256, 0, stream>>>(
          x, ldx, wA, C, nullptr, nullptr, p_PQ, N2, BN, C);
    } else {
      gemm_kernel<0><<<dim3(BN / 64, N2 / 64), 256, 0, stream>>>(
          x, ldx, wA, C, nullptr, nullptr, p_PQ, N2, BN, N2, C);
    }
    gather_max_kernel<<<BN, O, 0, stream>>>(p_PQ, p_idx, sc, bb, outp, ldo, O);
  };

  // ---- encoder ----
  edgeconv(points,     3,  3,   64,  p_wA1, s1, b1, p_xc + 0,   FD);
  edgeconv(p_xc + 0,   FD, 64,  64,  p_wA2, s2, b2, p_xc + 64,  FD);
  edgeconv(p_xc + 64,  FD, 64,  128, p_wA3, s3, b3, p_xc + 128, FD);
  edgeconv(p_xc + 128, FD, 128, 256, p_wA4, s4, b4, p_xc + 256, FD);

  // w5: split-bf16 MFMA (dist region now dead -> As planes live there)
  split3_kernel<<<2048, 256, 0, stream>>>(p_xc, p_As, APL, BN * FD);
  gemm_mfma512_kernel<1><<<dim3(BN / 128, 4), 256, 0, stream>>>(
      p_As, APL, p_w5s, WPL, s5, b5, p_H, BN);
  colmax_part_kernel<<<dim3(Bb, FD / 256, CMCH), 256, 0, stream>>>(p_H, p_part);
  colmax_final_kernel<<<dim3(Bb, FD / 256), 256, 0, stream>>>(p_part, p_feat);

  const int MD = Bb * Mm;  // 16200
  const int GXM = (MD + 127) / 128;
  // ---- fold 1 ----
  fb_kernel<<<1024, 256, 0, stream>>>(p_feat, f1w1, FD + 2, f1b1, p_fb);
  fold_l1_kernel<<<MD, FD, 0, stream>>>(p_fb, p_grid, 2, Mm, p_wt1, p_H);
  split3_kernel<<<2048, 256, 0, stream>>>(p_H, p_As, APL, MD * FD);
  gemm_mfma512_kernel<2><<<dim3(GXM, 4), 256, 0, stream>>>(
      p_As, APL, p_f1w2s, WPL, nullptr, f1b2, p_H2, MD);
  gemm_o3_kernel<<<(MD + 3) / 4, 256, 0, stream>>>(p_H2, f1w3, f1b3, p_fr1, MD);

  // ---- fold 2 ----
  fb_kernel<<<1024, 256, 0, stream>>>(p_feat, f2w1, FD + 3, f2b1, p_fb);
  fold_l1_kernel<<<MD, FD, 0, stream>>>(p_fb, p_fr1, 3, 0, p_wt2, p_H);
  split3_kernel<<<2048, 256, 0, stream>>>(p_H, p_As, APL, MD * FD);
  gemm_mfma512_kernel<2><<<dim3(GXM, 4), 256, 0, stream>>>(
      p_As, APL, p_f2w2s, WPL, nullptr, f2b2, p_H2, MD);
  gemm_o3_kernel<<<(MD + 3) / 4, 256, 0, stream>>>(p_H2, f2w3, f2b3, (float*)d_out, MD);
}